// Round 1
// baseline (302.916 us; speedup 1.0000x reference)
//
#include <hip/hip_runtime.h>
#include <hip/hip_bf16.h>

// Problem constants
#define NVOCAB 50257
#define PP     512
#define KK     64
#define BB     32
#define LLEN   2048
#define NPOS   (BB * LLEN)   // 65536

// ---------------------------------------------------------------------------
// Workspace layout (floats):
//   lhat_t : [512][64]          transposed normalized labels      32768
//   G      : [32][64][2048]     cosine sims                     4194304
//   mm     : [32][2048]         max-over-k of relu(conv+bias)     65536
//   beta   : [32][2048]         softmax over L                    65536
//   part   : [32*32][512]       partial pooled sums              524288
// total ~18.6 MB
// ---------------------------------------------------------------------------

__device__ inline unsigned int pack_bf2(float lo, float hi) {
    __hip_bfloat162 h = __float22bfloat162_rn(make_float2(lo, hi));
    unsigned int u;
    __builtin_memcpy(&u, &h, 4);
    return u;   // low 16 bits = lo, high 16 bits = hi
}

// K1: l_hat transposed: lhat_t[p*64 + k] = C[k][p] / ||C[k]||
__global__ void k1_lhat(const float* __restrict__ C, float* __restrict__ lhat_t) {
    const int k = blockIdx.x;
    const int t = threadIdx.x;
    float v0 = C[k * PP + t];
    float v1 = C[k * PP + t + 256];
    __shared__ float red[256];
    red[t] = v0 * v0 + v1 * v1;
    __syncthreads();
    for (int s = 128; s > 0; s >>= 1) {
        if (t < s) red[t] += red[t + s];
        __syncthreads();
    }
    const float inv = rsqrtf(red[0]);
    lhat_t[t * KK + k]         = v0 * inv;
    lhat_t[(t + 256) * KK + k] = v1 * inv;
}

// K2: G[b][k][l] = dot(emb_bf16 / ||emb_bf16||, l_hat[k])
// block = 256 thr (4 waves); block handles 64 consecutive positions x all 64 k.
// LDS: emb packed bf16x2, p-major with +1 pad: semb[p2*65 + pos].
// wave wv computes k in [wv*16, wv*16+16); lane = position.
__launch_bounds__(256)
__global__ void k2_gemm(const int* __restrict__ x, const float* __restrict__ V,
                        const float* __restrict__ lhat_t, float* __restrict__ G) {
    __shared__ unsigned int semb[256 * 65];   // 66560 B
    __shared__ int stok[64];

    const int tid  = threadIdx.x;
    const int lane = tid & 63;
    const int wv   = tid >> 6;
    const int posBase = blockIdx.x * 64;

    if (tid < 64) stok[tid] = x[posBase + tid];
    __syncthreads();

    // staging: wave wv stages rows [wv*16, wv*16+16)
    for (int i = 0; i < 16; ++i) {
        const int row = (wv << 4) + i;
        const float4* vp = (const float4*)(V + (long long)stok[row] * PP);
        float4 a  = vp[lane];        // p = 4*lane .. 4*lane+3
        float4 b4 = vp[64 + lane];   // p = 256 + 4*lane ..
        const int p2a = 2 * lane;
        semb[(p2a    ) * 65 + row] = pack_bf2(a.x, a.y);
        semb[(p2a + 1) * 65 + row] = pack_bf2(a.z, a.w);
        const int p2b = 128 + 2 * lane;
        semb[(p2b    ) * 65 + row] = pack_bf2(b4.x, b4.y);
        semb[(p2b + 1) * 65 + row] = pack_bf2(b4.z, b4.w);
    }
    __syncthreads();

    const int k0 = __builtin_amdgcn_readfirstlane(wv) * 16;  // wave-uniform
    const float* __restrict__ wbase = lhat_t + k0;

    float acc[16];
#pragma unroll
    for (int j = 0; j < 16; ++j) acc[j] = 0.f;
    float accn = 0.f;

#pragma unroll 2
    for (int p2 = 0; p2 < 256; ++p2) {
        const unsigned int wd = semb[p2 * 65 + lane];
        const float e0 = __uint_as_float(wd << 16);
        const float e1 = __uint_as_float(wd & 0xffff0000u);
        const float* wp = wbase + (p2 * 2) * KK;
#pragma unroll
        for (int j = 0; j < 16; ++j) acc[j] = fmaf(e0, wp[j], acc[j]);
#pragma unroll
        for (int j = 0; j < 16; ++j) acc[j] = fmaf(e1, wp[KK + j], acc[j]);
        accn = fmaf(e0, e0, fmaf(e1, e1, accn));
    }

    const float rn = rsqrtf(accn);
    const int b = blockIdx.x >> 5;            // 32 chunks of 64 per batch row
    const int l = (blockIdx.x & 31) * 64 + lane;
#pragma unroll
    for (int j = 0; j < 16; ++j)
        G[(b * KK + k0 + j) * LLEN + l] = acc[j] * rn;
}

// K3: mm[b][l] = max_k relu( conv11(G[b][k][:], f1_w)[l] + f1_b[k] )
__global__ void k3_convmax(const float* __restrict__ G, const float* __restrict__ f1w,
                           const float* __restrict__ f1b, float* __restrict__ mm) {
    const int b = blockIdx.x >> 3;
    const int l = (blockIdx.x & 7) * 256 + threadIdx.x;
    float w[11];
#pragma unroll
    for (int j = 0; j < 11; ++j) w[j] = f1w[j];
    float best = 0.f;
    for (int k = 0; k < KK; ++k) {
        const float* g = G + (b * KK + k) * LLEN;
        float u = 0.f;
#pragma unroll
        for (int j = 0; j < 11; ++j) {
            const int idx = l + j - 5;
            const float gv = (idx >= 0 && idx < LLEN) ? g[idx] : 0.f;
            u = fmaf(gv, w[j], u);
        }
        const float m = u + f1b[k];
        best = fmaxf(best, m > 0.f ? m : 0.f);
    }
    mm[b * LLEN + l] = best;
}

// K4: beta[b][:] = softmax(mm[b][:]) over L=2048; block per b, 8 elems/thread
__global__ void k4_softmax(const float* __restrict__ mm, float* __restrict__ beta) {
    const int b = blockIdx.x;
    const int t = threadIdx.x;
    __shared__ float red[256];
    float v[8];
    float mx = -1e30f;
#pragma unroll
    for (int i = 0; i < 8; ++i) {
        v[i] = mm[b * LLEN + t + i * 256];
        mx = fmaxf(mx, v[i]);
    }
    red[t] = mx;
    __syncthreads();
    for (int s = 128; s > 0; s >>= 1) {
        if (t < s) red[t] = fmaxf(red[t], red[t + s]);
        __syncthreads();
    }
    mx = red[0];
    __syncthreads();
    float sm = 0.f;
#pragma unroll
    for (int i = 0; i < 8; ++i) {
        v[i] = __expf(v[i] - mx);
        sm += v[i];
    }
    red[t] = sm;
    __syncthreads();
    for (int s = 128; s > 0; s >>= 1) {
        if (t < s) red[t] += red[t + s];
        __syncthreads();
    }
    const float inv = 1.f / red[0];
#pragma unroll
    for (int i = 0; i < 8; ++i) beta[b * LLEN + t + i * 256] = v[i] * inv;
}

// K5: partial pooled sums. block = (b, chunk of 64 l); part[blk][p] = sum_l beta*V[x]
__global__ void k5_partial(const int* __restrict__ x, const float* __restrict__ V,
                           const float* __restrict__ beta, float* __restrict__ part) {
    const int b  = blockIdx.x >> 5;
    const int c  = blockIdx.x & 31;
    const int t  = threadIdx.x;
    const int l0 = c * 64;
    float2 acc = make_float2(0.f, 0.f);
#pragma unroll 4
    for (int i = 0; i < 64; ++i) {
        const int l = l0 + i;
        const int tok   = x[b * LLEN + l];      // block-uniform -> scalar
        const float wgt = beta[b * LLEN + l];   // block-uniform -> scalar
        const float2* vp = (const float2*)(V + (long long)tok * PP);
        const float2 e = vp[t];
        acc.x = fmaf(wgt, e.x, acc.x);
        acc.y = fmaf(wgt, e.y, acc.y);
    }
    ((float2*)(part + (size_t)blockIdx.x * PP))[t] = acc;
}

// K6: pooled[b] = (1/L) * sum_chunks part; out[b][k] = dot(pooled, f2_w[k]) + f2_b[k]
__global__ void k6_final(const float* __restrict__ part, const float* __restrict__ f2w,
                         const float* __restrict__ f2b, float* __restrict__ out) {
    const int b = blockIdx.x;
    const int t = threadIdx.x;
    __shared__ float pl[PP];
    float s0 = 0.f, s1 = 0.f;
    for (int c = 0; c < 32; ++c) {
        const float* pp = part + (size_t)(b * 32 + c) * PP;
        s0 += pp[t];
        s1 += pp[t + 256];
    }
    pl[t]       = s0 * (1.f / 2048.f);
    pl[t + 256] = s1 * (1.f / 2048.f);
    __syncthreads();
    const int lane = t & 63;
    const int wv   = t >> 6;
    for (int i = 0; i < 16; ++i) {
        const int k = wv * 16 + i;
        const float* fw = f2w + k * PP;
        float p = 0.f;
#pragma unroll
        for (int m = 0; m < 8; ++m)
            p = fmaf(pl[lane + m * 64], fw[lane + m * 64], p);
#pragma unroll
        for (int off = 32; off > 0; off >>= 1) p += __shfl_down(p, off, 64);
        if (lane == 0) out[b * KK + k] = p + f2b[k];
    }
}

extern "C" void kernel_launch(void* const* d_in, const int* in_sizes, int n_in,
                              void* d_out, int out_size, void* d_ws, size_t ws_size,
                              hipStream_t stream) {
    const int*   x   = (const int*)d_in[0];
    const float* V   = (const float*)d_in[1];
    const float* C   = (const float*)d_in[2];
    const float* f1w = (const float*)d_in[3];
    const float* f1b = (const float*)d_in[4];
    const float* f2w = (const float*)d_in[5];
    const float* f2b = (const float*)d_in[6];
    float* out = (float*)d_out;

    float* ws   = (float*)d_ws;
    float* lhat = ws;                       // 32768
    float* G    = lhat + PP * KK;           // 4194304
    float* mm   = G + (size_t)BB * KK * LLEN; // 65536
    float* beta = mm + BB * LLEN;           // 65536
    float* part = beta + BB * LLEN;         // 524288

    k1_lhat   <<<KK,   256, 0, stream>>>(C, lhat);
    k2_gemm   <<<NPOS / 64, 256, 0, stream>>>(x, V, lhat, G);
    k3_convmax<<<BB * (LLEN / 256), 256, 0, stream>>>(G, f1w, f1b, mm);
    k4_softmax<<<BB,   256, 0, stream>>>(mm, beta);
    k5_partial<<<BB * 32, 256, 0, stream>>>(x, V, beta, part);
    k6_final  <<<BB,   256, 0, stream>>>(part, f2w, f2b, out);
}

// Round 2
// 233.078 us; speedup vs baseline: 1.2996x; 1.2996x over previous
//
#include <hip/hip_runtime.h>
#include <hip/hip_bf16.h>

#define PP     512
#define KK     64
#define BB     32
#define LLEN   2048
#define NPOS   (BB * LLEN)   // 65536

typedef __attribute__((ext_vector_type(8)))  short short8;
typedef __attribute__((ext_vector_type(16))) float float16;

__device__ inline unsigned int pack_bf2(float lo, float hi) {
    __hip_bfloat162 h = __float22bfloat162_rn(make_float2(lo, hi));
    unsigned int u;
    __builtin_memcpy(&u, &h, 4);
    return u;   // low 16 = lo, high 16 = hi
}

// ---------------------------------------------------------------------------
// K1: normalize label rows and write bf16 B-operand fragments:
//   lhatB[(f*64 + n)*8 + j] = bf16( C[n][k= f*8+j] / ||C[n]|| ),  f=k/8, j=k%8
// ---------------------------------------------------------------------------
__global__ void k1_lhat(const float* __restrict__ C, ushort* __restrict__ lhatB) {
    const int n = blockIdx.x;
    const int t = threadIdx.x;
    float v0 = C[n * PP + t];
    float v1 = C[n * PP + t + 256];
    __shared__ float red[256];
    red[t] = v0 * v0 + v1 * v1;
    __syncthreads();
    for (int s = 128; s > 0; s >>= 1) {
        if (t < s) red[t] += red[t + s];
        __syncthreads();
    }
    const float inv = rsqrtf(red[0]);
    const int ka = t, kb = t + 256;
    lhatB[(((ka >> 3) * 64 + n) << 3) + (ka & 7)] = (ushort)(pack_bf2(v0 * inv, 0.f) & 0xffffu);
    lhatB[(((kb >> 3) * 64 + n) << 3) + (kb & 7)] = (ushort)(pack_bf2(v1 * inv, 0.f) & 0xffffu);
}

// ---------------------------------------------------------------------------
// K2: MFMA bf16 GEMM. Block: 128 positions x 64 labels, K=512 in 4 chunks of 128.
// Wave w owns m-tile [w*32, w*32+32); computes both 32-wide n-tiles.
// A LDS layout: slot(m, f ^ (m&7)) of 16B, conflict-free read+write.
// B LDS layout: slot(f, n), linear copy from k1's fragment buffer.
// Output G^T[pos][k] fp32 (pos = b*2048 + l), row-normalized by bf16-rounded norm.
// ---------------------------------------------------------------------------
__launch_bounds__(256)
__global__ void k2_gemm(const int* __restrict__ x, const float* __restrict__ V,
                        const uint4* __restrict__ lhatB4, float* __restrict__ Gt) {
    __shared__ uint4 sA[128 * 16];   // 32 KB
    __shared__ uint4 sB[16 * 64];    // 16 KB
    __shared__ int   stok[128];
    __shared__ float rnorm[128];

    const int tid  = threadIdx.x;
    const int lane = tid & 63;
    const int wv   = tid >> 6;

    if (tid < 128) stok[tid] = x[blockIdx.x * 128 + tid];

    float16 acc0, acc1;
#pragma unroll
    for (int i = 0; i < 16; ++i) { acc0[i] = 0.f; acc1[i] = 0.f; }
    float nacc[8];
#pragma unroll
    for (int i = 0; i < 8; ++i) nacc[i] = 0.f;

    for (int kc = 0; kc < 4; ++kc) {
        __syncthreads();
        // ---- stage A chunk: 128 pos x 128 k -> bf16 fragments ----
#pragma unroll
        for (int i = 0; i < 8; ++i) {
            const int m = i * 16 + (tid >> 4);
            const int f = tid & 15;
            const float* src = V + (size_t)stok[m] * PP + kc * 128 + f * 8;
            const float4 a = ((const float4*)src)[0];
            const float4 b = ((const float4*)src)[1];
            uint4 wq;
            wq.x = pack_bf2(a.x, a.y); wq.y = pack_bf2(a.z, a.w);
            wq.z = pack_bf2(b.x, b.y); wq.w = pack_bf2(b.z, b.w);
            sA[m * 16 + (f ^ (m & 7))] = wq;
            // norm of the bf16-rounded values (consistent with what mfma sees)
            float s2 = 0.f, e;
            e = __uint_as_float(wq.x << 16);          s2 = fmaf(e, e, s2);
            e = __uint_as_float(wq.x & 0xffff0000u);  s2 = fmaf(e, e, s2);
            e = __uint_as_float(wq.y << 16);          s2 = fmaf(e, e, s2);
            e = __uint_as_float(wq.y & 0xffff0000u);  s2 = fmaf(e, e, s2);
            e = __uint_as_float(wq.z << 16);          s2 = fmaf(e, e, s2);
            e = __uint_as_float(wq.z & 0xffff0000u);  s2 = fmaf(e, e, s2);
            e = __uint_as_float(wq.w << 16);          s2 = fmaf(e, e, s2);
            e = __uint_as_float(wq.w & 0xffff0000u);  s2 = fmaf(e, e, s2);
            nacc[i] += s2;
        }
        // ---- stage B chunk (already fragment-order bf16 in global) ----
#pragma unroll
        for (int i = 0; i < 4; ++i)
            sB[i * 256 + tid] = lhatB4[kc * 1024 + i * 256 + tid];

        if (kc == 3) {
            // finalize per-position norms: reduce across the 16 threads per row
#pragma unroll
            for (int i = 0; i < 8; ++i) {
                float r = nacc[i];
                r += __shfl_down(r, 8, 16);
                r += __shfl_down(r, 4, 16);
                r += __shfl_down(r, 2, 16);
                r += __shfl_down(r, 1, 16);
                if ((tid & 15) == 0) rnorm[i * 16 + (tid >> 4)] = rsqrtf(r);
            }
        }
        __syncthreads();

        // ---- MFMA inner loop: 8 K-steps of 16 ----
#pragma unroll
        for (int kb = 0; kb < 8; ++kb) {
            const int f  = kb * 2 + (lane >> 5);
            const int mq = wv * 32 + (lane & 31);
            const uint4 av = sA[mq * 16 + (f ^ (mq & 7))];
            const uint4 b0 = sB[f * 64 + (lane & 31)];
            const uint4 b1 = sB[f * 64 + 32 + (lane & 31)];
            short8 a8, s0, s1;
            __builtin_memcpy(&a8, &av, 16);
            __builtin_memcpy(&s0, &b0, 16);
            __builtin_memcpy(&s1, &b1, 16);
            acc0 = __builtin_amdgcn_mfma_f32_32x32x16_bf16(a8, s0, acc0, 0, 0, 0);
            acc1 = __builtin_amdgcn_mfma_f32_32x32x16_bf16(a8, s1, acc1, 0, 0, 0);
        }
    }

    // ---- epilogue: scale rows by rnorm, store G^T[pos][k] ----
    const size_t posBase = (size_t)blockIdx.x * 128;
#pragma unroll
    for (int reg = 0; reg < 16; ++reg) {
        const int r  = (reg & 3) + 8 * (reg >> 2) + 4 * (lane >> 5);
        const int mq = wv * 32 + r;
        const float rn = rnorm[mq];
        const size_t p = posBase + mq;
        Gt[p * 64 + (lane & 31)]      = acc0[reg] * rn;
        Gt[p * 64 + 32 + (lane & 31)] = acc1[reg] * rn;
    }
}

// ---------------------------------------------------------------------------
// K3: mm[b][l] = max_k relu(conv11(G)[l] + f1b[k]) on G^T layout.
// lane = k (64); wave-level max reduce; taps stride 256B, L1-resident.
// ---------------------------------------------------------------------------
__global__ void k3_convmax(const float* __restrict__ Gt, const float* __restrict__ f1w,
                           const float* __restrict__ f1b, float* __restrict__ mm) {
    const int b    = blockIdx.x >> 6;
    const int l0   = (blockIdx.x & 63) * 32;
    const int lane = threadIdx.x & 63;
    const int wvi  = threadIdx.x >> 6;
    float w[11];
#pragma unroll
    for (int j = 0; j < 11; ++j) w[j] = f1w[j];
    const float bias = f1b[lane];
    for (int li = wvi; li < 32; li += 4) {
        const int l = l0 + li;
        float u = 0.f;
#pragma unroll
        for (int j = 0; j < 11; ++j) {
            const int idx = l + j - 5;
            if (idx >= 0 && idx < LLEN)
                u = fmaf(Gt[((size_t)b * LLEN + idx) * 64 + lane], w[j], u);
        }
        float m = u + bias;
        m = m > 0.f ? m : 0.f;
#pragma unroll
        for (int off = 32; off > 0; off >>= 1)
            m = fmaxf(m, __shfl_xor(m, off, 64));
        if (lane == 0) mm[b * LLEN + l] = m;
    }
}

// K4: softmax over L per batch row
__global__ void k4_softmax(const float* __restrict__ mm, float* __restrict__ beta) {
    const int b = blockIdx.x;
    const int t = threadIdx.x;
    __shared__ float red[256];
    float v[8];
    float mx = -1e30f;
#pragma unroll
    for (int i = 0; i < 8; ++i) {
        v[i] = mm[b * LLEN + t + i * 256];
        mx = fmaxf(mx, v[i]);
    }
    red[t] = mx;
    __syncthreads();
    for (int s = 128; s > 0; s >>= 1) {
        if (t < s) red[t] = fmaxf(red[t], red[t + s]);
        __syncthreads();
    }
    mx = red[0];
    __syncthreads();
    float sm = 0.f;
#pragma unroll
    for (int i = 0; i < 8; ++i) {
        v[i] = __expf(v[i] - mx);
        sm += v[i];
    }
    red[t] = sm;
    __syncthreads();
    for (int s = 128; s > 0; s >>= 1) {
        if (t < s) red[t] += red[t + s];
        __syncthreads();
    }
    const float inv = 1.f / red[0];
#pragma unroll
    for (int i = 0; i < 8; ++i) beta[b * LLEN + t + i * 256] = v[i] * inv;
}

// K5: partial pooled sums: part[blk][p] = sum_{l in chunk} beta[b][l] * V[x[b][l]][p]
__global__ void k5_partial(const int* __restrict__ x, const float* __restrict__ V,
                           const float* __restrict__ beta, float* __restrict__ part) {
    const int b  = blockIdx.x >> 5;
    const int c  = blockIdx.x & 31;
    const int t  = threadIdx.x;
    const int l0 = c * 64;
    float2 acc = make_float2(0.f, 0.f);
#pragma unroll 4
    for (int i = 0; i < 64; ++i) {
        const int l = l0 + i;
        const int tok   = x[b * LLEN + l];
        const float wgt = beta[b * LLEN + l];
        const float2* vp = (const float2*)(V + (size_t)tok * PP);
        const float2 e = vp[t];
        acc.x = fmaf(wgt, e.x, acc.x);
        acc.y = fmaf(wgt, e.y, acc.y);
    }
    ((float2*)(part + (size_t)blockIdx.x * PP))[t] = acc;
}

// K6: reduce partials, apply head: out[b][k] = dot(pooled, f2_w[k]) + f2_b[k]
__global__ void k6_final(const float* __restrict__ part, const float* __restrict__ f2w,
                         const float* __restrict__ f2b, float* __restrict__ out) {
    const int b = blockIdx.x;
    const int t = threadIdx.x;
    __shared__ float pl[PP];
    float s0 = 0.f, s1 = 0.f;
    for (int c = 0; c < 32; ++c) {
        const float* pp = part + (size_t)(b * 32 + c) * PP;
        s0 += pp[t];
        s1 += pp[t + 256];
    }
    pl[t]       = s0 * (1.f / 2048.f);
    pl[t + 256] = s1 * (1.f / 2048.f);
    __syncthreads();
    const int lane = t & 63;
    const int wv   = t >> 6;
    for (int i = 0; i < 16; ++i) {
        const int k = wv * 16 + i;
        const float* fw = f2w + k * PP;
        float p = 0.f;
#pragma unroll
        for (int m = 0; m < 8; ++m)
            p = fmaf(pl[lane + m * 64], fw[lane + m * 64], p);
#pragma unroll
        for (int off = 32; off > 0; off >>= 1) p += __shfl_down(p, off, 64);
        if (lane == 0) out[b * KK + k] = p + f2b[k];
    }
}

extern "C" void kernel_launch(void* const* d_in, const int* in_sizes, int n_in,
                              void* d_out, int out_size, void* d_ws, size_t ws_size,
                              hipStream_t stream) {
    const int*   x   = (const int*)d_in[0];
    const float* V   = (const float*)d_in[1];
    const float* C   = (const float*)d_in[2];
    const float* f1w = (const float*)d_in[3];
    const float* f1b = (const float*)d_in[4];
    const float* f2w = (const float*)d_in[5];
    const float* f2b = (const float*)d_in[6];
    float* out = (float*)d_out;

    float* ws = (float*)d_ws;
    ushort* lhatB = (ushort*)ws;                    // 32768 ushort = 16384 floats
    float* Gt   = ws + 16384;                       // 65536*64 fp32 (G transposed)
    float* mm   = Gt + (size_t)NPOS * KK;           // 65536
    float* beta = mm + NPOS;                        // 65536
    float* part = beta + NPOS;                      // 32*32*512

    k1_lhat   <<<KK, 256, 0, stream>>>(C, lhatB);
    k2_gemm   <<<NPOS / 128, 256, 0, stream>>>(x, V, (const uint4*)lhatB, Gt);
    k3_convmax<<<BB * (LLEN / 32), 256, 0, stream>>>(Gt, f1w, f1b, mm);
    k4_softmax<<<BB, 256, 0, stream>>>(mm, beta);
    k5_partial<<<BB * 32, 256, 0, stream>>>(x, V, beta, part);
    k6_final  <<<BB, 256, 0, stream>>>(part, f2w, f2b, out);
}

// Round 3
// 199.158 us; speedup vs baseline: 1.5210x; 1.1703x over previous
//
#include <hip/hip_runtime.h>
#include <hip/hip_bf16.h>

#define PP     512
#define KK     64
#define BB     32
#define LLEN   2048
#define NPOS   (BB * LLEN)   // 65536

typedef __attribute__((ext_vector_type(8)))  short short8;
typedef __attribute__((ext_vector_type(16))) float float16;

__device__ inline unsigned int pack_bf2(float lo, float hi) {
    __hip_bfloat162 h = __float22bfloat162_rn(make_float2(lo, hi));
    unsigned int u;
    __builtin_memcpy(&u, &h, 4);
    return u;   // low 16 = lo, high 16 = hi
}
__device__ inline float bf_lo(unsigned int v) { return __uint_as_float(v << 16); }
__device__ inline float bf_hi(unsigned int v) { return __uint_as_float(v & 0xffff0000u); }

// ---------------------------------------------------------------------------
// K1: build bf16 B-operand fragments for both GEMMs.
//   blocks 0..63   : lhatB[n] = C[n]/||C[n]||   (normalized labels)
//   blocks 64..127 : f2wB[n]  = f2_w[n]         (head weights, unnormalized)
// Fragment layout: dst[((p>>3)*64 + n)*8 + (p&7)] = bf16(src[n][p])
// ---------------------------------------------------------------------------
__global__ void k1_prep(const float* __restrict__ C, const float* __restrict__ f2w,
                        ushort* __restrict__ lhatB, ushort* __restrict__ f2wB) {
    const int n   = blockIdx.x & 63;
    const bool isW = blockIdx.x >= 64;
    const float* src = isW ? (f2w + n * PP) : (C + n * PP);
    ushort* dst = isW ? f2wB : lhatB;
    const int t = threadIdx.x;
    float v0 = src[t];
    float v1 = src[t + 256];
    __shared__ float red[256];
    red[t] = v0 * v0 + v1 * v1;
    __syncthreads();
    for (int s = 128; s > 0; s >>= 1) {
        if (t < s) red[t] += red[t + s];
        __syncthreads();
    }
    const float inv = isW ? 1.f : rsqrtf(red[0]);
    dst[(((t >> 3)      * 64 + n) << 3) + (t & 7)] = (ushort)(pack_bf2(v0 * inv, 0.f) & 0xffffu);
    dst[(((t >> 3) + 32) * 64 + n) * 8  + (t & 7)] = (ushort)(pack_bf2(v1 * inv, 0.f) & 0xffffu);
}

// ---------------------------------------------------------------------------
// K2: fused double MFMA GEMM. Block: 128 positions x 64 labels.
//   Gt2[pos][j] = pack( cos(pos, j), cos(pos, j+32) )       (normalized)
//   E2p[pos][j] = pack( emb.f2w[j],  emb.f2w[j+32] )        (raw emb)
// ---------------------------------------------------------------------------
__launch_bounds__(256)
__global__ void k2_gemm(const int* __restrict__ x, const float* __restrict__ V,
                        const uint4* __restrict__ lhatB4, const uint4* __restrict__ f2wB4,
                        unsigned int* __restrict__ Gt2, unsigned int* __restrict__ E2p) {
    __shared__ uint4 sA[128 * 16];   // 32 KB
    __shared__ uint4 sB[16 * 64];    // 16 KB (lhat chunk)
    __shared__ uint4 sB2[16 * 64];   // 16 KB (f2w chunk)
    __shared__ int   stok[128];
    __shared__ float rnorm[128];

    const int tid  = threadIdx.x;
    const int lane = tid & 63;
    const int wv   = tid >> 6;

    if (tid < 128) stok[tid] = x[blockIdx.x * 128 + tid];

    float16 acc0, acc1, acc2, acc3;
#pragma unroll
    for (int i = 0; i < 16; ++i) { acc0[i] = 0.f; acc1[i] = 0.f; acc2[i] = 0.f; acc3[i] = 0.f; }
    float nacc[8];
#pragma unroll
    for (int i = 0; i < 8; ++i) nacc[i] = 0.f;

    for (int kc = 0; kc < 4; ++kc) {
        __syncthreads();
        // ---- stage A chunk: 128 pos x 128 p -> bf16 fragments, xor-swizzled ----
#pragma unroll
        for (int i = 0; i < 8; ++i) {
            const int m = i * 16 + (tid >> 4);
            const int f = tid & 15;
            const float* src = V + (size_t)stok[m] * PP + kc * 128 + f * 8;
            const float4 a = ((const float4*)src)[0];
            const float4 b = ((const float4*)src)[1];
            uint4 wq;
            wq.x = pack_bf2(a.x, a.y); wq.y = pack_bf2(a.z, a.w);
            wq.z = pack_bf2(b.x, b.y); wq.w = pack_bf2(b.z, b.w);
            sA[m * 16 + (f ^ (m & 7))] = wq;
            float s2 = 0.f, e;
            e = bf_lo(wq.x); s2 = fmaf(e, e, s2);  e = bf_hi(wq.x); s2 = fmaf(e, e, s2);
            e = bf_lo(wq.y); s2 = fmaf(e, e, s2);  e = bf_hi(wq.y); s2 = fmaf(e, e, s2);
            e = bf_lo(wq.z); s2 = fmaf(e, e, s2);  e = bf_hi(wq.z); s2 = fmaf(e, e, s2);
            e = bf_lo(wq.w); s2 = fmaf(e, e, s2);  e = bf_hi(wq.w); s2 = fmaf(e, e, s2);
            nacc[i] += s2;
        }
        // ---- stage both B chunks (fragment-order bf16 in global) ----
#pragma unroll
        for (int i = 0; i < 4; ++i) {
            sB [i * 256 + tid] = lhatB4[kc * 1024 + i * 256 + tid];
            sB2[i * 256 + tid] = f2wB4 [kc * 1024 + i * 256 + tid];
        }

        if (kc == 3) {
#pragma unroll
            for (int i = 0; i < 8; ++i) {
                float r = nacc[i];
                r += __shfl_down(r, 8, 16);
                r += __shfl_down(r, 4, 16);
                r += __shfl_down(r, 2, 16);
                r += __shfl_down(r, 1, 16);
                if ((tid & 15) == 0) rnorm[i * 16 + (tid >> 4)] = rsqrtf(r);
            }
        }
        __syncthreads();

        // ---- MFMA inner loop: 8 K-steps of 16, 4 MFMAs each ----
#pragma unroll
        for (int kb = 0; kb < 8; ++kb) {
            const int f  = kb * 2 + (lane >> 5);
            const int mq = wv * 32 + (lane & 31);
            const uint4 av = sA[mq * 16 + (f ^ (mq & 7))];
            const uint4 b0 = sB [f * 64 + (lane & 31)];
            const uint4 b1 = sB [f * 64 + 32 + (lane & 31)];
            const uint4 c0 = sB2[f * 64 + (lane & 31)];
            const uint4 c1 = sB2[f * 64 + 32 + (lane & 31)];
            short8 a8, t0, t1, t2, t3;
            __builtin_memcpy(&a8, &av, 16);
            __builtin_memcpy(&t0, &b0, 16);
            __builtin_memcpy(&t1, &b1, 16);
            __builtin_memcpy(&t2, &c0, 16);
            __builtin_memcpy(&t3, &c1, 16);
            acc0 = __builtin_amdgcn_mfma_f32_32x32x16_bf16(a8, t0, acc0, 0, 0, 0);
            acc1 = __builtin_amdgcn_mfma_f32_32x32x16_bf16(a8, t1, acc1, 0, 0, 0);
            acc2 = __builtin_amdgcn_mfma_f32_32x32x16_bf16(a8, t2, acc2, 0, 0, 0);
            acc3 = __builtin_amdgcn_mfma_f32_32x32x16_bf16(a8, t3, acc3, 0, 0, 0);
        }
    }

    // ---- epilogue: pack bf16 pairs (k, k+32) and store ----
    const size_t posBase = (size_t)blockIdx.x * 128;
#pragma unroll
    for (int reg = 0; reg < 16; ++reg) {
        const int r  = (reg & 3) + 8 * (reg >> 2) + 4 * (lane >> 5);
        const int mq = wv * 32 + r;
        const float rn = rnorm[mq];
        const size_t p = posBase + mq;
        Gt2[p * 32 + (lane & 31)] = pack_bf2(acc0[reg] * rn, acc1[reg] * rn);
        E2p[p * 32 + (lane & 31)] = pack_bf2(acc2[reg], acc3[reg]);
    }
}

// ---------------------------------------------------------------------------
// K3: mm[b][l] = max_k relu(conv11(G)[l] + f1b[k]), packed-bf16 Gt2 input.
// Block: one b, 128 l. LDS tile 138 rows x 32 uints, +1 pad stride.
// Half-wave = one l: lane j holds k=j and k=j+32.
// ---------------------------------------------------------------------------
__global__ void k3_convmax(const unsigned int* __restrict__ Gt2, const float* __restrict__ f1w,
                           const float* __restrict__ f1b, float* __restrict__ mm) {
    __shared__ unsigned int sT[138 * 33];
    const int b  = blockIdx.x >> 4;
    const int l0 = (blockIdx.x & 15) * 128;
    const int t  = threadIdx.x;
    for (int idx = t; idx < 138 * 32; idx += 256) {
        const int row = idx >> 5, col = idx & 31;
        const int gl = l0 - 5 + row;
        sT[row * 33 + col] = (gl >= 0 && gl < LLEN)
            ? Gt2[((size_t)b * LLEN + gl) * 32 + col] : 0u;
    }
    __syncthreads();
    float w[11];
#pragma unroll
    for (int j = 0; j < 11; ++j) w[j] = f1w[j];
    const int j = t & 31;
    const int h = t >> 5;                 // 0..7 half-wave index
    const float bias0 = f1b[j], bias1 = f1b[j + 32];
#pragma unroll 2
    for (int i = 0; i < 16; ++i) {
        const int lr = i * 8 + h;         // 0..127
        float u0 = 0.f, u1 = 0.f;
#pragma unroll
        for (int tap = 0; tap < 11; ++tap) {
            const unsigned int v = sT[(lr + tap) * 33 + j];
            u0 = fmaf(bf_lo(v), w[tap], u0);
            u1 = fmaf(bf_hi(v), w[tap], u1);
        }
        float m = fmaxf(fmaxf(u0 + bias0, 0.f), fmaxf(u1 + bias1, 0.f));
#pragma unroll
        for (int off = 16; off > 0; off >>= 1)
            m = fmaxf(m, __shfl_xor(m, off, 64));
        if (j == 0) mm[b * LLEN + l0 + lr] = m;
    }
}

// K4: softmax over L per batch row
__global__ void k4_softmax(const float* __restrict__ mm, float* __restrict__ beta) {
    const int b = blockIdx.x;
    const int t = threadIdx.x;
    __shared__ float red[256];
    float v[8];
    float mx = -1e30f;
#pragma unroll
    for (int i = 0; i < 8; ++i) {
        v[i] = mm[b * LLEN + t + i * 256];
        mx = fmaxf(mx, v[i]);
    }
    red[t] = mx;
    __syncthreads();
    for (int s = 128; s > 0; s >>= 1) {
        if (t < s) red[t] = fmaxf(red[t], red[t + s]);
        __syncthreads();
    }
    mx = red[0];
    __syncthreads();
    float sm = 0.f;
#pragma unroll
    for (int i = 0; i < 8; ++i) {
        v[i] = __expf(v[i] - mx);
        sm += v[i];
    }
    red[t] = sm;
    __syncthreads();
    for (int s = 128; s > 0; s >>= 1) {
        if (t < s) red[t] += red[t + s];
        __syncthreads();
    }
    const float inv = 1.f / red[0];
#pragma unroll
    for (int i = 0; i < 8; ++i) beta[b * LLEN + t + i * 256] = v[i] * inv;
}

// K5: part2[b*8+c][k] = sum_{l in chunk c} beta[b][l] * E2[b,l][k]
__global__ void k5_pool(const unsigned int* __restrict__ E2p, const float* __restrict__ beta,
                        float* __restrict__ part2) {
    const int b = blockIdx.x >> 3;
    const int c = blockIdx.x & 7;
    const int t = threadIdx.x;
    const int j = t & 31, h = t >> 5;
    float a0 = 0.f, a1 = 0.f;
    const int lbase = c * 256;
#pragma unroll 4
    for (int i = 0; i < 32; ++i) {
        const int l = lbase + i * 8 + h;
        const float wgt = beta[b * LLEN + l];
        const unsigned int v = E2p[((size_t)b * LLEN + l) * 32 + j];
        a0 = fmaf(wgt, bf_lo(v), a0);
        a1 = fmaf(wgt, bf_hi(v), a1);
    }
    __shared__ float s[8][64];
    s[h][j]      = a0;
    s[h][j + 32] = a1;
    __syncthreads();
    if (t < 64) {
        float r = 0.f;
#pragma unroll
        for (int hh = 0; hh < 8; ++hh) r += s[hh][t];
        part2[blockIdx.x * 64 + t] = r;
    }
}

// K6: out[b][k] = (1/L) * sum_c part2[b*8+c][k] + f2b[k]
__global__ void k6_final(const float* __restrict__ part2, const float* __restrict__ f2b,
                         float* __restrict__ out) {
    const int o = blockIdx.x * 256 + threadIdx.x;   // 2048 outputs
    const int k = o & 63;
    const int b = o >> 6;
    float r = 0.f;
#pragma unroll
    for (int c = 0; c < 8; ++c) r += part2[(b * 8 + c) * 64 + k];
    out[o] = r * (1.f / 2048.f) + f2b[k];
}

extern "C" void kernel_launch(void* const* d_in, const int* in_sizes, int n_in,
                              void* d_out, int out_size, void* d_ws, size_t ws_size,
                              hipStream_t stream) {
    const int*   x   = (const int*)d_in[0];
    const float* V   = (const float*)d_in[1];
    const float* C   = (const float*)d_in[2];
    const float* f1w = (const float*)d_in[3];
    const float* f1b = (const float*)d_in[4];
    const float* f2w = (const float*)d_in[5];
    const float* f2b = (const float*)d_in[6];
    float* out = (float*)d_out;

    float* ws = (float*)d_ws;
    ushort* lhatB = (ushort*)ws;                                // 16384 floats
    ushort* f2wB  = (ushort*)(ws + 16384);                      // 16384 floats
    unsigned int* Gt2 = (unsigned int*)(ws + 32768);            // NPOS*32 uints
    unsigned int* E2p = Gt2 + (size_t)NPOS * 32;                // NPOS*32 uints
    float* mm    = (float*)(E2p + (size_t)NPOS * 32);           // 65536
    float* beta  = mm + NPOS;                                   // 65536
    float* part2 = beta + NPOS;                                 // 256*64

    k1_prep   <<<128, 256, 0, stream>>>(C, f2w, lhatB, f2wB);
    k2_gemm   <<<NPOS / 128, 256, 0, stream>>>(x, V, (const uint4*)lhatB, (const uint4*)f2wB, Gt2, E2p);
    k3_convmax<<<BB * (LLEN / 128), 256, 0, stream>>>(Gt2, f1w, f1b, mm);
    k4_softmax<<<BB, 256, 0, stream>>>(mm, beta);
    k5_pool   <<<BB * 8, 256, 0, stream>>>(E2p, beta, part2);
    k6_final  <<<8, 256, 0, stream>>>(part2, f2b, out);
}